// Round 1
// baseline (3471.455 us; speedup 1.0000x reference)
//
#include <hip/hip_runtime.h>

// Olmo3 MLP (no activation): y = down( (x@gate^T * gs) * (x@up^T * us) ) * ds
// H=4096, I=11008, M=B*S=8192. All GEMMs bf16 MFMA 16x16x32, m97 structure:
// 128x128 tile, BK=64, 4 waves/block each 64x64, global_load_lds width=16.
//
// ws layout (requires ~494 MiB):
//   [0,          64M)  x as bf16            [M,H]
//   [64M,       150M)  gate_w bf16          [I,H]
//   [150M,      236M)  up_w bf16            [I,H]
//   [236M,      322M)  down_w bf16          [H,I]
//   [322M,      494M)  t = g*u bf16         [M,I]

#define H_DIM 4096
#define I_DIM 11008
#define M_DIM 8192

typedef __bf16 bf16;
typedef __bf16 bf16x8 __attribute__((ext_vector_type(8)));
typedef float f32x4 __attribute__((ext_vector_type(4)));

#define GAS __attribute__((address_space(1)))
#define LAS __attribute__((address_space(3)))

__device__ __forceinline__ void async_ld16(const void* g, void* l) {
    __builtin_amdgcn_global_load_lds((const GAS void*)g, (LAS void*)l, 16, 0, 0);
}

// ---------------- prep: dtype conversion ----------------

__global__ __launch_bounds__(256) void cvt_i32_bf16_k(const int* __restrict__ src,
                                                      ushort* __restrict__ dst, int n4) {
    int t = blockIdx.x * 256 + threadIdx.x;
    if (t >= n4) return;
    const int4 v = ((const int4*)src)[t];
    ushort4 o;
    o.x = __builtin_bit_cast(ushort, (bf16)(float)v.x);
    o.y = __builtin_bit_cast(ushort, (bf16)(float)v.y);
    o.z = __builtin_bit_cast(ushort, (bf16)(float)v.z);
    o.w = __builtin_bit_cast(ushort, (bf16)(float)v.w);
    ((ushort4*)dst)[t] = o;
}

__global__ __launch_bounds__(256) void cvt_f32_bf16_k(const float* __restrict__ src,
                                                      ushort* __restrict__ dst, int n4) {
    int t = blockIdx.x * 256 + threadIdx.x;
    if (t >= n4) return;
    const float4 v = ((const float4*)src)[t];
    ushort4 o;
    o.x = __builtin_bit_cast(ushort, (bf16)v.x);
    o.y = __builtin_bit_cast(ushort, (bf16)v.y);
    o.z = __builtin_bit_cast(ushort, (bf16)v.z);
    o.w = __builtin_bit_cast(ushort, (bf16)v.w);
    ((ushort4*)dst)[t] = o;
}

// ---------------- fused gate+up GEMM ----------------
// C tile 128(m) x 128(i); A = x_bf16 [M,H], B = {gate,up} [I,H] (B^T layout:
// both operand fragments are contiguous-in-K ds_read_b128).
// t[m,i] = bf16( (accg*gs[i]) * (accu*us[i]) )

__global__ __launch_bounds__(256, 2) void gemm_gateup(
    const bf16* __restrict__ X, const bf16* __restrict__ WG, const bf16* __restrict__ WU,
    const float* __restrict__ GS, const float* __restrict__ US, ushort* __restrict__ T) {
    __shared__ bf16x8 As[128 * 8];
    __shared__ bf16x8 Bg[128 * 8];
    __shared__ bf16x8 Bu[128 * 8];

    const int tid = threadIdx.x;
    const int lane = tid & 63;
    const int wave = tid >> 6;
    const int wm = wave & 1, wn = wave >> 1;
    const int m0 = blockIdx.x * 128;
    const int i0 = blockIdx.y * 128;

    f32x4 accg[4][4] = {};
    f32x4 accu[4][4] = {};

    const int srow = lane >> 3;        // row within 8-row chunk
    const int scol = (lane & 7) * 8;   // k element offset within row

    for (int k0 = 0; k0 < H_DIM; k0 += 64) {
        // stage 48 KiB (3 tiles x 16 chunks of 1 KiB), 12 chunks per wave
        for (int c = wave; c < 48; c += 4) {
            const int buf = c >> 4, cc = c & 15;
            const int row = cc * 8 + srow;
            const bf16* src;
            char* base;
            if (buf == 0)      { src = X  + (size_t)(m0 + row) * H_DIM + k0 + scol; base = (char*)As; }
            else if (buf == 1) { src = WG + (size_t)(i0 + row) * H_DIM + k0 + scol; base = (char*)Bg; }
            else               { src = WU + (size_t)(i0 + row) * H_DIM + k0 + scol; base = (char*)Bu; }
            async_ld16(src, base + cc * 1024);
        }
        __syncthreads();
#pragma unroll
        for (int kk = 0; kk < 2; ++kk) {
            const int kv = kk * 4 + (lane >> 4);
            bf16x8 a[4], bg[4], bu[4];
#pragma unroll
            for (int mi = 0; mi < 4; ++mi)
                a[mi] = As[(wm * 64 + mi * 16 + (lane & 15)) * 8 + kv];
#pragma unroll
            for (int ni = 0; ni < 4; ++ni) {
                bg[ni] = Bg[(wn * 64 + ni * 16 + (lane & 15)) * 8 + kv];
                bu[ni] = Bu[(wn * 64 + ni * 16 + (lane & 15)) * 8 + kv];
            }
#pragma unroll
            for (int mi = 0; mi < 4; ++mi)
#pragma unroll
                for (int ni = 0; ni < 4; ++ni) {
                    accg[mi][ni] = __builtin_amdgcn_mfma_f32_16x16x32_bf16(a[mi], bg[ni], accg[mi][ni], 0, 0, 0);
                    accu[mi][ni] = __builtin_amdgcn_mfma_f32_16x16x32_bf16(a[mi], bu[ni], accu[mi][ni], 0, 0, 0);
                }
        }
        __syncthreads();
    }

    // epilogue: C/D layout col=lane&15, row=(lane>>4)*4+r (m89-verified)
#pragma unroll
    for (int ni = 0; ni < 4; ++ni) {
        const int col = i0 + wn * 64 + ni * 16 + (lane & 15);
        const float gsv = GS[col], usv = US[col];
#pragma unroll
        for (int mi = 0; mi < 4; ++mi) {
            const int row0 = m0 + wm * 64 + mi * 16 + (lane >> 4) * 4;
#pragma unroll
            for (int r = 0; r < 4; ++r) {
                float g = accg[mi][ni][r] * gsv;
                float u = accu[mi][ni][r] * usv;
                T[(size_t)(row0 + r) * I_DIM + col] = __builtin_bit_cast(ushort, (bf16)(g * u));
            }
        }
    }
}

// ---------------- down GEMM ----------------
// A = t [M,I] bf16, B = down_w [H,I] bf16, K=I=11008, out fp32 y * ds[h]

__global__ __launch_bounds__(256, 2) void gemm_down(
    const bf16* __restrict__ T, const bf16* __restrict__ WD,
    const float* __restrict__ DS, float* __restrict__ Y) {
    __shared__ bf16x8 As[128 * 8];
    __shared__ bf16x8 Bs[128 * 8];

    const int tid = threadIdx.x;
    const int lane = tid & 63;
    const int wave = tid >> 6;
    const int wm = wave & 1, wn = wave >> 1;
    const int m0 = blockIdx.x * 128;
    const int n0 = blockIdx.y * 128;

    f32x4 acc[4][4] = {};

    const int srow = lane >> 3;
    const int scol = (lane & 7) * 8;

    for (int k0 = 0; k0 < I_DIM; k0 += 64) {
        for (int c = wave; c < 32; c += 4) {
            const int buf = c >> 4, cc = c & 15;
            const int row = cc * 8 + srow;
            const bf16* src;
            char* base;
            if (buf == 0) { src = T  + (size_t)(m0 + row) * I_DIM + k0 + scol; base = (char*)As; }
            else          { src = WD + (size_t)(n0 + row) * I_DIM + k0 + scol; base = (char*)Bs; }
            async_ld16(src, base + cc * 1024);
        }
        __syncthreads();
#pragma unroll
        for (int kk = 0; kk < 2; ++kk) {
            const int kv = kk * 4 + (lane >> 4);
            bf16x8 a[4], b[4];
#pragma unroll
            for (int mi = 0; mi < 4; ++mi)
                a[mi] = As[(wm * 64 + mi * 16 + (lane & 15)) * 8 + kv];
#pragma unroll
            for (int ni = 0; ni < 4; ++ni)
                b[ni] = Bs[(wn * 64 + ni * 16 + (lane & 15)) * 8 + kv];
#pragma unroll
            for (int mi = 0; mi < 4; ++mi)
#pragma unroll
                for (int ni = 0; ni < 4; ++ni)
                    acc[mi][ni] = __builtin_amdgcn_mfma_f32_16x16x32_bf16(a[mi], b[ni], acc[mi][ni], 0, 0, 0);
        }
        __syncthreads();
    }

#pragma unroll
    for (int ni = 0; ni < 4; ++ni) {
        const int col = n0 + wn * 64 + ni * 16 + (lane & 15);
        const float dsv = DS[col];
#pragma unroll
        for (int mi = 0; mi < 4; ++mi) {
            const int row0 = m0 + wm * 64 + mi * 16 + (lane >> 4) * 4;
#pragma unroll
            for (int r = 0; r < 4; ++r)
                Y[(size_t)(row0 + r) * H_DIM + col] = acc[mi][ni][r] * dsv;
        }
    }
}

// ---------------- launch ----------------

extern "C" void kernel_launch(void* const* d_in, const int* in_sizes, int n_in,
                              void* d_out, int out_size, void* d_ws, size_t ws_size,
                              hipStream_t stream) {
    const float* x   = (const float*)d_in[0];
    const int*   gwq = (const int*)d_in[1];
    const float* gs  = (const float*)d_in[2];
    const int*   uwq = (const int*)d_in[3];
    const float* us  = (const float*)d_in[4];
    const int*   dwq = (const int*)d_in[5];
    const float* ds  = (const float*)d_in[6];
    float* y = (float*)d_out;

    char* ws = (char*)d_ws;
    bf16*   ws_x  = (bf16*)(ws);                              // 67,108,864 B
    bf16*   ws_gw = (bf16*)(ws + 67108864ull);                // 90,177,536 B
    bf16*   ws_uw = (bf16*)(ws + 157286400ull);               // 90,177,536 B
    bf16*   ws_dw = (bf16*)(ws + 247463936ull);               // 90,177,536 B
    ushort* ws_t  = (ushort*)(ws + 337641472ull);             // 180,355,072 B

    const int nx4 = M_DIM * H_DIM / 4;   // 8,388,608 -> 32768 blocks
    const int nw4 = I_DIM * H_DIM / 4;   // 11,272,192 -> 44032 blocks

    cvt_f32_bf16_k<<<nx4 / 256, 256, 0, stream>>>(x, (ushort*)ws_x, nx4);
    cvt_i32_bf16_k<<<nw4 / 256, 256, 0, stream>>>(gwq, (ushort*)ws_gw, nw4);
    cvt_i32_bf16_k<<<nw4 / 256, 256, 0, stream>>>(uwq, (ushort*)ws_uw, nw4);
    cvt_i32_bf16_k<<<nw4 / 256, 256, 0, stream>>>(dwq, (ushort*)ws_dw, nw4);

    gemm_gateup<<<dim3(M_DIM / 128, I_DIM / 128), 256, 0, stream>>>(ws_x, ws_gw, ws_uw, gs, us, ws_t);
    gemm_down<<<dim3(M_DIM / 128, H_DIM / 128), 256, 0, stream>>>((const bf16*)ws_t, ws_dw, ds, y);
}

// Round 2
// 3071.071 us; speedup vs baseline: 1.1304x; 1.1304x over previous
//
#include <hip/hip_runtime.h>

// Olmo3 MLP (no activation): y = down( (x@gate^T * gs) * (x@up^T * us) ) * ds
// H=4096, I=11008, M=B*S=8192. All GEMMs bf16 MFMA 16x16x32, m97 structure:
// 128x128 tile, BK=64, 4 waves/block each 64x64, global_load_lds width=16.
//
// R2: XOR-swizzled LDS layout (phys col = kv ^ (row&7)) to kill the 16-way
// bank conflict on operand ds_read_b128 (R1: SQ_LDS_BANK_CONFLICT=4.06e8).
// Swizzle applied on the staging SOURCE address (global_load_lds dst is
// wave-uniform base + lane*16, can't scatter), unswizzled at read time.
//
// ws layout (requires ~494 MiB):
//   [0,          64M)  x as bf16            [M,H]
//   [64M,       150M)  gate_w bf16          [I,H]
//   [150M,      236M)  up_w bf16            [I,H]
//   [236M,      322M)  down_w bf16          [H,I]
//   [322M,      494M)  t = g*u bf16         [M,I]

#define H_DIM 4096
#define I_DIM 11008
#define M_DIM 8192

typedef __bf16 bf16;
typedef __bf16 bf16x8 __attribute__((ext_vector_type(8)));
typedef float f32x4 __attribute__((ext_vector_type(4)));

#define GAS __attribute__((address_space(1)))
#define LAS __attribute__((address_space(3)))

__device__ __forceinline__ void async_ld16(const void* g, void* l) {
    __builtin_amdgcn_global_load_lds((const GAS void*)g, (LAS void*)l, 16, 0, 0);
}

// ---------------- prep: dtype conversion ----------------

__global__ __launch_bounds__(256) void cvt_i32_bf16_k(const int* __restrict__ src,
                                                      ushort* __restrict__ dst, int n4) {
    int t = blockIdx.x * 256 + threadIdx.x;
    if (t >= n4) return;
    const int4 v = ((const int4*)src)[t];
    ushort4 o;
    o.x = __builtin_bit_cast(ushort, (bf16)(float)v.x);
    o.y = __builtin_bit_cast(ushort, (bf16)(float)v.y);
    o.z = __builtin_bit_cast(ushort, (bf16)(float)v.z);
    o.w = __builtin_bit_cast(ushort, (bf16)(float)v.w);
    ((ushort4*)dst)[t] = o;
}

__global__ __launch_bounds__(256) void cvt_f32_bf16_k(const float* __restrict__ src,
                                                      ushort* __restrict__ dst, int n4) {
    int t = blockIdx.x * 256 + threadIdx.x;
    if (t >= n4) return;
    const float4 v = ((const float4*)src)[t];
    ushort4 o;
    o.x = __builtin_bit_cast(ushort, (bf16)v.x);
    o.y = __builtin_bit_cast(ushort, (bf16)v.y);
    o.z = __builtin_bit_cast(ushort, (bf16)v.z);
    o.w = __builtin_bit_cast(ushort, (bf16)v.w);
    ((ushort4*)dst)[t] = o;
}

// ---------------- fused gate+up GEMM ----------------
// C tile 128(m) x 128(i); A = x_bf16 [M,H], B = {gate,up} [I,H] (B^T layout).
// t[m,i] = bf16( (accg*gs[i]) * (accu*us[i]) )

__global__ __launch_bounds__(256, 2) void gemm_gateup(
    const bf16* __restrict__ X, const bf16* __restrict__ WG, const bf16* __restrict__ WU,
    const float* __restrict__ GS, const float* __restrict__ US, ushort* __restrict__ T) {
    __shared__ bf16x8 As[128 * 8];
    __shared__ bf16x8 Bg[128 * 8];
    __shared__ bf16x8 Bu[128 * 8];

    const int tid = threadIdx.x;
    const int lane = tid & 63;
    const int wave = tid >> 6;
    const int wm = wave & 1, wn = wave >> 1;
    const int m0 = blockIdx.x * 128;
    const int i0 = blockIdx.y * 128;

    f32x4 accg[4][4] = {};
    f32x4 accu[4][4] = {};

    const int srow = lane >> 3;                         // row within 8-row chunk
    const int scol = ((lane & 7) ^ (lane >> 3)) * 8;    // SWIZZLED src k-chunk

    for (int k0 = 0; k0 < H_DIM; k0 += 64) {
        // stage 48 KiB (3 tiles x 16 chunks of 1 KiB), 12 chunks per wave
        for (int c = wave; c < 48; c += 4) {
            const int buf = c >> 4, cc = c & 15;
            const int row = cc * 8 + srow;
            const bf16* src;
            char* base;
            if (buf == 0)      { src = X  + (size_t)(m0 + row) * H_DIM + k0 + scol; base = (char*)As; }
            else if (buf == 1) { src = WG + (size_t)(i0 + row) * H_DIM + k0 + scol; base = (char*)Bg; }
            else               { src = WU + (size_t)(i0 + row) * H_DIM + k0 + scol; base = (char*)Bu; }
            async_ld16(src, base + cc * 1024);
        }
        __syncthreads();
#pragma unroll
        for (int kk = 0; kk < 2; ++kk) {
            const int kv = kk * 4 + (lane >> 4);
            bf16x8 a[4], bg[4], bu[4];
#pragma unroll
            for (int mi = 0; mi < 4; ++mi) {
                const int row = wm * 64 + mi * 16 + (lane & 15);
                a[mi] = As[row * 8 + (kv ^ (row & 7))];
            }
#pragma unroll
            for (int ni = 0; ni < 4; ++ni) {
                const int row = wn * 64 + ni * 16 + (lane & 15);
                bg[ni] = Bg[row * 8 + (kv ^ (row & 7))];
                bu[ni] = Bu[row * 8 + (kv ^ (row & 7))];
            }
#pragma unroll
            for (int mi = 0; mi < 4; ++mi)
#pragma unroll
                for (int ni = 0; ni < 4; ++ni) {
                    accg[mi][ni] = __builtin_amdgcn_mfma_f32_16x16x32_bf16(a[mi], bg[ni], accg[mi][ni], 0, 0, 0);
                    accu[mi][ni] = __builtin_amdgcn_mfma_f32_16x16x32_bf16(a[mi], bu[ni], accu[mi][ni], 0, 0, 0);
                }
        }
        __syncthreads();
    }

    // epilogue: C/D layout col=lane&15, row=(lane>>4)*4+r (m89-verified)
#pragma unroll
    for (int ni = 0; ni < 4; ++ni) {
        const int col = i0 + wn * 64 + ni * 16 + (lane & 15);
        const float gsv = GS[col], usv = US[col];
#pragma unroll
        for (int mi = 0; mi < 4; ++mi) {
            const int row0 = m0 + wm * 64 + mi * 16 + (lane >> 4) * 4;
#pragma unroll
            for (int r = 0; r < 4; ++r) {
                float g = accg[mi][ni][r] * gsv;
                float u = accu[mi][ni][r] * usv;
                T[(size_t)(row0 + r) * I_DIM + col] = __builtin_bit_cast(ushort, (bf16)(g * u));
            }
        }
    }
}

// ---------------- down GEMM ----------------
// A = t [M,I] bf16, B = down_w [H,I] bf16, K=I=11008, out fp32 y * ds[h]

__global__ __launch_bounds__(256, 2) void gemm_down(
    const bf16* __restrict__ T, const bf16* __restrict__ WD,
    const float* __restrict__ DS, float* __restrict__ Y) {
    __shared__ bf16x8 As[128 * 8];
    __shared__ bf16x8 Bs[128 * 8];

    const int tid = threadIdx.x;
    const int lane = tid & 63;
    const int wave = tid >> 6;
    const int wm = wave & 1, wn = wave >> 1;
    const int m0 = blockIdx.x * 128;
    const int n0 = blockIdx.y * 128;

    f32x4 acc[4][4] = {};

    const int srow = lane >> 3;
    const int scol = ((lane & 7) ^ (lane >> 3)) * 8;    // SWIZZLED src k-chunk

    for (int k0 = 0; k0 < I_DIM; k0 += 64) {
        for (int c = wave; c < 32; c += 4) {
            const int buf = c >> 4, cc = c & 15;
            const int row = cc * 8 + srow;
            const bf16* src;
            char* base;
            if (buf == 0) { src = T  + (size_t)(m0 + row) * I_DIM + k0 + scol; base = (char*)As; }
            else          { src = WD + (size_t)(n0 + row) * I_DIM + k0 + scol; base = (char*)Bs; }
            async_ld16(src, base + cc * 1024);
        }
        __syncthreads();
#pragma unroll
        for (int kk = 0; kk < 2; ++kk) {
            const int kv = kk * 4 + (lane >> 4);
            bf16x8 a[4], b[4];
#pragma unroll
            for (int mi = 0; mi < 4; ++mi) {
                const int row = wm * 64 + mi * 16 + (lane & 15);
                a[mi] = As[row * 8 + (kv ^ (row & 7))];
            }
#pragma unroll
            for (int ni = 0; ni < 4; ++ni) {
                const int row = wn * 64 + ni * 16 + (lane & 15);
                b[ni] = Bs[row * 8 + (kv ^ (row & 7))];
            }
#pragma unroll
            for (int mi = 0; mi < 4; ++mi)
#pragma unroll
                for (int ni = 0; ni < 4; ++ni)
                    acc[mi][ni] = __builtin_amdgcn_mfma_f32_16x16x32_bf16(a[mi], b[ni], acc[mi][ni], 0, 0, 0);
        }
        __syncthreads();
    }

#pragma unroll
    for (int ni = 0; ni < 4; ++ni) {
        const int col = n0 + wn * 64 + ni * 16 + (lane & 15);
        const float dsv = DS[col];
#pragma unroll
        for (int mi = 0; mi < 4; ++mi) {
            const int row0 = m0 + wm * 64 + mi * 16 + (lane >> 4) * 4;
#pragma unroll
            for (int r = 0; r < 4; ++r)
                Y[(size_t)(row0 + r) * H_DIM + col] = acc[mi][ni][r] * dsv;
        }
    }
}

// ---------------- launch ----------------

extern "C" void kernel_launch(void* const* d_in, const int* in_sizes, int n_in,
                              void* d_out, int out_size, void* d_ws, size_t ws_size,
                              hipStream_t stream) {
    const float* x   = (const float*)d_in[0];
    const int*   gwq = (const int*)d_in[1];
    const float* gs  = (const float*)d_in[2];
    const int*   uwq = (const int*)d_in[3];
    const float* us  = (const float*)d_in[4];
    const int*   dwq = (const int*)d_in[5];
    const float* ds  = (const float*)d_in[6];
    float* y = (float*)d_out;

    char* ws = (char*)d_ws;
    bf16*   ws_x  = (bf16*)(ws);                              // 67,108,864 B
    bf16*   ws_gw = (bf16*)(ws + 67108864ull);                // 90,177,536 B
    bf16*   ws_uw = (bf16*)(ws + 157286400ull);               // 90,177,536 B
    bf16*   ws_dw = (bf16*)(ws + 247463936ull);               // 90,177,536 B
    ushort* ws_t  = (ushort*)(ws + 337641472ull);             // 180,355,072 B

    const int nx4 = M_DIM * H_DIM / 4;   // 8,388,608 -> 32768 blocks
    const int nw4 = I_DIM * H_DIM / 4;   // 11,272,192 -> 44032 blocks

    cvt_f32_bf16_k<<<nx4 / 256, 256, 0, stream>>>(x, (ushort*)ws_x, nx4);
    cvt_i32_bf16_k<<<nw4 / 256, 256, 0, stream>>>(gwq, (ushort*)ws_gw, nw4);
    cvt_i32_bf16_k<<<nw4 / 256, 256, 0, stream>>>(uwq, (ushort*)ws_uw, nw4);
    cvt_i32_bf16_k<<<nw4 / 256, 256, 0, stream>>>(dwq, (ushort*)ws_dw, nw4);

    gemm_gateup<<<dim3(M_DIM / 128, I_DIM / 128), 256, 0, stream>>>(ws_x, ws_gw, ws_uw, gs, us, ws_t);
    gemm_down<<<dim3(M_DIM / 128, H_DIM / 128), 256, 0, stream>>>((const bf16*)ws_t, ws_dw, ds, y);
}